// Round 3
// baseline (367.344 us; speedup 1.0000x reference)
//
#include <hip/hip_runtime.h>
#include <math.h>

// Problem constants (fixed by the reference setup)
#define NTOT 32768
#define NB   64
#define NPB  512      // rows per segment
#define DQK  128
#define MF   256      // feature count m
#define DVV  256      // value dim

#define QK_SCALE   0.29730177875068026f   // 128^-0.25
#define INV_SQRT_M 0.0625f                // 1/sqrt(256)
#define EPS_PHI    1e-4f
#define EPS_NORM   1e-8f

static __device__ __forceinline__ float red_max32(float v) {
    v = fmaxf(v, __shfl_xor(v, 1, 64));
    v = fmaxf(v, __shfl_xor(v, 2, 64));
    v = fmaxf(v, __shfl_xor(v, 4, 64));
    v = fmaxf(v, __shfl_xor(v, 8, 64));
    v = fmaxf(v, __shfl_xor(v, 16, 64));
    return v;
}
static __device__ __forceinline__ float red_sum32(float v) {
    v += __shfl_xor(v, 1, 64);
    v += __shfl_xor(v, 2, 64);
    v += __shfl_xor(v, 4, 64);
    v += __shfl_xor(v, 8, 64);
    v += __shfl_xor(v, 16, 64);
    return v;
}

// ---------------------------------------------------------------------------
// Kernel 1: U = (X * d^-1/4) @ omega  [64 rows x all 256 cols per block]
// 256 threads: tx = tid&31, ty = tid>>5. 8x8 micro.
// B-frag columns split (tx*4, 128+tx*4) to avoid 8-way LDS conflicts.
//   IS_QUERY: out = Qp; aux = norm.   else: out = U - h; aux = rowmax(U)
// ---------------------------------------------------------------------------
template <bool IS_QUERY>
__global__ __launch_bounds__(256) void phi_kernel(
    const float* __restrict__ X, const float* __restrict__ omega,
    const float* __restrict__ Ksum,
    float* __restrict__ out, float* __restrict__ aux)
{
    __shared__ __align__(16) float xs[64][132];   // row-major
    __shared__ __align__(16) float oms[16][256];  // k-major omega chunk
    __shared__ float KsS[256];

    const int tid = threadIdx.x;
    const int tx  = tid & 31;
    const int ty  = tid >> 5;
    const int row0 = blockIdx.x * 64;

    if (IS_QUERY) KsS[tid] = Ksum[(row0 >> 9) * MF + tid];

    // ---- stage X tile (64x128), scaled, row-major ----
    {
        const float4* Xv = (const float4*)(X + (size_t)row0 * DQK);
        #pragma unroll
        for (int j = 0; j < 8; ++j) {
            int idx = tid + 256 * j;
            int r = idx >> 5, c4 = idx & 31;
            float4 v = Xv[idx];
            v.x *= QK_SCALE; v.y *= QK_SCALE; v.z *= QK_SCALE; v.w *= QK_SCALE;
            *(float4*)&xs[r][c4 * 4] = v;
        }
    }

    float acc[8][8] = {};
    float h[8] = {};

    const float4* Ov = (const float4*)omega;
    float4 oreg[4];
    #pragma unroll
    for (int j = 0; j < 4; ++j) oreg[j] = Ov[tid + 256 * j];

    for (int c = 0; c < 8; ++c) {
        __syncthreads();
        #pragma unroll
        for (int j = 0; j < 4; ++j) {
            int idx = tid + 256 * j;
            *(float4*)&oms[idx >> 6][(idx & 63) * 4] = oreg[j];
        }
        __syncthreads();
        if (c < 7) {
            #pragma unroll
            for (int j = 0; j < 4; ++j)
                oreg[j] = Ov[(c + 1) * 1024 + tid + 256 * j];
        }
        const int kc = c * 16;
        #pragma unroll
        for (int kq = 0; kq < 4; ++kq) {
            float4 a4[8];
            #pragma unroll
            for (int i = 0; i < 8; ++i)
                a4[i] = *(const float4*)&xs[ty * 8 + i][kc + kq * 4];
            #pragma unroll
            for (int t = 0; t < 4; ++t) {
                const int kk = kq * 4 + t;
                float4 b0 = *(const float4*)&oms[kk][tx * 4];
                float4 b1 = *(const float4*)&oms[kk][128 + tx * 4];
                float bv[8] = {b0.x, b0.y, b0.z, b0.w, b1.x, b1.y, b1.z, b1.w};
                #pragma unroll
                for (int i = 0; i < 8; ++i) {
                    const float av = ((const float*)&a4[i])[t];
                    h[i] = fmaf(av, av, h[i]);
                    #pragma unroll
                    for (int j = 0; j < 8; ++j)
                        acc[i][j] = fmaf(av, bv[j], acc[i][j]);
                }
            }
        }
    }

    // ---- epilogue (acc cols j<4 -> tx*4+j, j>=4 -> 128+tx*4+j-4) ----
    #pragma unroll
    for (int i = 0; i < 8; ++i) {
        const int grow = row0 + ty * 8 + i;
        float mx = acc[i][0];
        #pragma unroll
        for (int j = 1; j < 8; ++j) mx = fmaxf(mx, acc[i][j]);
        mx = red_max32(mx);
        const float hv = 0.5f * h[i];

        if (IS_QUERY) {
            const float hm = hv + mx;
            float q[8];
            #pragma unroll
            for (int j = 0; j < 8; ++j)
                q[j] = (__expf(acc[i][j] - hm) + EPS_PHI) * INV_SQRT_M;
            float4 o0 = {q[0], q[1], q[2], q[3]};
            float4 o1 = {q[4], q[5], q[6], q[7]};
            *(float4*)&out[(size_t)grow * MF + tx * 4]       = o0;
            *(float4*)&out[(size_t)grow * MF + 128 + tx * 4] = o1;
            float np = 0.f;
            #pragma unroll
            for (int j = 0; j < 4; ++j) np = fmaf(q[j], KsS[tx * 4 + j], np);
            #pragma unroll
            for (int j = 0; j < 4; ++j) np = fmaf(q[4 + j], KsS[128 + tx * 4 + j], np);
            np = red_sum32(np);
            if (tx == 0) aux[grow] = np;
        } else {
            float4 o0 = {acc[i][0] - hv, acc[i][1] - hv, acc[i][2] - hv, acc[i][3] - hv};
            float4 o1 = {acc[i][4] - hv, acc[i][5] - hv, acc[i][6] - hv, acc[i][7] - hv};
            *(float4*)&out[(size_t)grow * MF + tx * 4]       = o0;
            *(float4*)&out[(size_t)grow * MF + 128 + tx * 4] = o1;
            if (tx == 0) aux[grow] = mx;
        }
    }
}

// ---------------------------------------------------------------------------
// Kernel 2: segmax[b] = max over 512 rows of rmax
// ---------------------------------------------------------------------------
__global__ __launch_bounds__(256) void segmax_kernel(
    const float* __restrict__ rmax, float* __restrict__ segmax)
{
    const int b = blockIdx.x, tid = threadIdx.x;
    float v = fmaxf(rmax[b * NPB + tid], rmax[b * NPB + 256 + tid]);
    v = red_max32(v);
    v = fmaxf(v, __shfl_xor(v, 32, 64));
    __shared__ float red[4];
    if ((tid & 63) == 0) red[tid >> 6] = v;
    __syncthreads();
    if (tid == 0)
        segmax[b] = fmaxf(fmaxf(red[0], red[1]), fmaxf(red[2], red[3]));
}

// ---------------------------------------------------------------------------
// Kernel 3: KV[b] = Kp_b^T @ V_b, one 128x128 tile per block, NO atomics.
// 1024 threads = 4 groups of 256; group g reduces n-rows [g*128, g*128+128)
// through its OWN 32KB LDS stage (4x(Kps+Vs) = 128KB total) -> 16 waves/block
// = 4 waves/SIMD. NOTE: __launch_bounds__(1024) WITHOUT a min-waves hint —
// the (1024,4) variant capped VGPRs at 64 and spilled acc[8][8] to scratch
// (rocprof: WRITE_SIZE 120MB vs 17MB of real output). 16-wave block implies
// <=128 VGPR launchability cap, which is exactly what this kernel needs.
// Register partials combined through LDS; group 0 stores the tile.
// vt==0 blocks also produce Ksum via per-group partials + LDS reduce.
// ---------------------------------------------------------------------------
__global__ __launch_bounds__(1024) void kv_kernel(
    const float* __restrict__ A, const float* __restrict__ V,
    const float* __restrict__ segmax,
    float* __restrict__ KV, float* __restrict__ Ksum)
{
    __shared__ __align__(16) float Kps[4][32][128];   // 64 KB
    __shared__ __align__(16) float Vs [4][32][128];   // 64 KB

    const int tall = threadIdx.x;
    const int g    = tall >> 8;        // n-group 0..3
    const int tid  = tall & 255;
    const int tx = tid & 15, ty = tid >> 4;
    const int vt = blockIdx.x, mt = blockIdx.y, b = blockIdx.z;
    const int m0 = mt * 128, v0 = vt * 128;
    const size_t n0 = (size_t)b * NPB + g * 128;
    const float smax = segmax[b];

    const int ln  = tid >> 5;     // 0..7  (n within chunk, +8j)
    const int lm4 = tid & 31;     // float4 column

    float acc[8][8] = {};
    float4 ks4 = {0.f, 0.f, 0.f, 0.f};

    float4 areg[4], vreg[4];
    #pragma unroll
    for (int j = 0; j < 4; ++j) {
        const size_t n = n0 + ln + 8 * j;
        areg[j] = *(const float4*)&A[n * MF + m0 + lm4 * 4];
        vreg[j] = *(const float4*)&V[n * DVV + v0 + lm4 * 4];
    }

    for (int c = 0; c < 4; ++c) {
        __syncthreads();
        #pragma unroll
        for (int j = 0; j < 4; ++j) {
            float4 e;
            e.x = (__expf(areg[j].x - smax) + EPS_PHI) * INV_SQRT_M;
            e.y = (__expf(areg[j].y - smax) + EPS_PHI) * INV_SQRT_M;
            e.z = (__expf(areg[j].z - smax) + EPS_PHI) * INV_SQRT_M;
            e.w = (__expf(areg[j].w - smax) + EPS_PHI) * INV_SQRT_M;
            ks4.x += e.x; ks4.y += e.y; ks4.z += e.z; ks4.w += e.w;
            *(float4*)&Kps[g][ln + 8 * j][lm4 * 4] = e;
            *(float4*)&Vs [g][ln + 8 * j][lm4 * 4] = vreg[j];
        }
        __syncthreads();
        if (c < 3) {
            #pragma unroll
            for (int j = 0; j < 4; ++j) {
                const size_t n = n0 + (c + 1) * 32 + ln + 8 * j;
                areg[j] = *(const float4*)&A[n * MF + m0 + lm4 * 4];
                vreg[j] = *(const float4*)&V[n * DVV + v0 + lm4 * 4];
            }
        }
        #pragma unroll 8
        for (int kk = 0; kk < 32; ++kk) {
            float4 a0 = *(const float4*)&Kps[g][kk][ty * 8];
            float4 a1 = *(const float4*)&Kps[g][kk][ty * 8 + 4];
            float4 b0 = *(const float4*)&Vs[g][kk][tx * 4];
            float4 b1 = *(const float4*)&Vs[g][kk][64 + tx * 4];
            float av[8] = {a0.x, a0.y, a0.z, a0.w, a1.x, a1.y, a1.z, a1.w};
            float bv[8] = {b0.x, b0.y, b0.z, b0.w, b1.x, b1.y, b1.z, b1.w};
            #pragma unroll
            for (int i = 0; i < 8; ++i)
                #pragma unroll
                for (int j = 0; j < 8; ++j)
                    acc[i][j] = fmaf(av[i], bv[j], acc[i][j]);
        }
    }

    // ---- cross-group combine into group 0 (LDS, conflict-free layout) ----
    float4* scr4 = (float4*)&Kps[0][0][0];        // 16 x 256 float4 = 64 KB
    for (int gg = 1; gg < 4; ++gg) {
        __syncthreads();
        if (g == gg) {
            #pragma unroll
            for (int i = 0; i < 8; ++i) {
                float4 q0 = {acc[i][0], acc[i][1], acc[i][2], acc[i][3]};
                float4 q1 = {acc[i][4], acc[i][5], acc[i][6], acc[i][7]};
                scr4[(i * 2 + 0) * 256 + tid] = q0;
                scr4[(i * 2 + 1) * 256 + tid] = q1;
            }
        }
        __syncthreads();
        if (g == 0) {
            #pragma unroll
            for (int i = 0; i < 8; ++i) {
                float4 q0 = scr4[(i * 2 + 0) * 256 + tid];
                float4 q1 = scr4[(i * 2 + 1) * 256 + tid];
                acc[i][0] += q0.x; acc[i][1] += q0.y; acc[i][2] += q0.z; acc[i][3] += q0.w;
                acc[i][4] += q1.x; acc[i][5] += q1.y; acc[i][6] += q1.z; acc[i][7] += q1.w;
            }
        }
    }

    if (g == 0) {
        #pragma unroll
        for (int i = 0; i < 8; ++i) {
            const size_t base = ((size_t)b * MF + m0 + ty * 8 + i) * DVV + v0;
            float4 o0 = {acc[i][0], acc[i][1], acc[i][2], acc[i][3]};
            float4 o1 = {acc[i][4], acc[i][5], acc[i][6], acc[i][7]};
            *(float4*)&KV[base + tx * 4]      = o0;
            *(float4*)&KV[base + 64 + tx * 4] = o1;
        }
    }

    // ---- Ksum: per-group partials -> LDS (Vs region) -> 128-thread reduce ----
    float* kscr = &Vs[0][0][0];                   // [4][8][128]
    *(float4*)&kscr[(g * 8 + ln) * 128 + lm4 * 4] = ks4;
    __syncthreads();
    if (vt == 0 && g == 0 && tid < 128) {
        float s = 0.f;
        #pragma unroll
        for (int r = 0; r < 32; ++r) s += kscr[r * 128 + tid];
        Ksum[b * MF + m0 + tid] = s;
    }
}

// ---------------------------------------------------------------------------
// Kernel 4: out = (Qp @ KV[b]) / (norm + eps). 128 rows x 128 v per block,
// 8x8 micro, m-chunk 32, register-prefetch pipeline.
// A-frag rows split (ty*4, 64+ty*4); B-frag cols split (tx*4, 64+tx*4).
// ---------------------------------------------------------------------------
__global__ __launch_bounds__(256) void out_kernel(
    const float* __restrict__ Qp, const float* __restrict__ KVm,
    const float* __restrict__ normv, float* __restrict__ out)
{
    __shared__ __align__(16) float Qs[128][36];   // row-major
    __shared__ __align__(16) float KVs[32][128];  // k-major
    __shared__ float nrmS[128];

    const int tid = threadIdx.x;
    const int tx = tid & 15, ty = tid >> 4;
    const int vt = blockIdx.x, rt = blockIdx.y, b = blockIdx.z;
    const int v0 = vt * 128;
    const int r0 = b * NPB + rt * 128;

    if (tid < 128) nrmS[tid] = normv[r0 + tid];

    const int qr  = tid >> 3;     // 0..31 (+32j)
    const int qm4 = tid & 7;
    const int km  = tid >> 5;     // 0..7  (+8j)
    const int kv4 = tid & 31;

    float acc[8][8] = {};

    float4 qreg[4], kreg[4];
    #pragma unroll
    for (int j = 0; j < 4; ++j) {
        qreg[j] = *(const float4*)&Qp[(size_t)(r0 + qr + 32 * j) * MF + qm4 * 4];
        kreg[j] = *(const float4*)&KVm[((size_t)b * MF + km + 8 * j) * DVV + v0 + kv4 * 4];
    }

    for (int c = 0; c < 8; ++c) {
        __syncthreads();
        #pragma unroll
        for (int j = 0; j < 4; ++j) {
            *(float4*)&Qs[qr + 32 * j][qm4 * 4]  = qreg[j];
            *(float4*)&KVs[km + 8 * j][kv4 * 4] = kreg[j];
        }
        __syncthreads();
        if (c < 7) {
            const int mc = (c + 1) * 32;
            #pragma unroll
            for (int j = 0; j < 4; ++j) {
                qreg[j] = *(const float4*)&Qp[(size_t)(r0 + qr + 32 * j) * MF + mc + qm4 * 4];
                kreg[j] = *(const float4*)&KVm[((size_t)b * MF + mc + km + 8 * j) * DVV + v0 + kv4 * 4];
            }
        }
        #pragma unroll 2
        for (int kq = 0; kq < 8; ++kq) {
            float4 a4[8];
            #pragma unroll
            for (int i = 0; i < 4; ++i)
                a4[i] = *(const float4*)&Qs[ty * 4 + i][kq * 4];
            #pragma unroll
            for (int i = 0; i < 4; ++i)
                a4[4 + i] = *(const float4*)&Qs[64 + ty * 4 + i][kq * 4];
            #pragma unroll
            for (int t = 0; t < 4; ++t) {
                const int kk = kq * 4 + t;
                float4 b0 = *(const float4*)&KVs[kk][tx * 4];
                float4 b1 = *(const float4*)&KVs[kk][64 + tx * 4];
                float bv[8] = {b0.x, b0.y, b0.z, b0.w, b1.x, b1.y, b1.z, b1.w};
                #pragma unroll
                for (int i = 0; i < 8; ++i) {
                    const float av = ((const float*)&a4[i])[t];
                    #pragma unroll
                    for (int j = 0; j < 8; ++j)
                        acc[i][j] = fmaf(av, bv[j], acc[i][j]);
                }
            }
        }
    }

    #pragma unroll
    for (int i = 0; i < 8; ++i) {
        const int row = (i < 4) ? (ty * 4 + i) : (64 + ty * 4 + i - 4);
        const float inv = 1.0f / (nrmS[row] + EPS_NORM);
        float4 o0 = {acc[i][0] * inv, acc[i][1] * inv, acc[i][2] * inv, acc[i][3] * inv};
        float4 o1 = {acc[i][4] * inv, acc[i][5] * inv, acc[i][6] * inv, acc[i][7] * inv};
        const size_t base = (size_t)(r0 + row) * DVV + v0;
        *(float4*)&out[base + tx * 4]      = o0;
        *(float4*)&out[base + 64 + tx * 4] = o1;
    }
}

// ---------------------------------------------------------------------------
extern "C" void kernel_launch(void* const* d_in, const int* in_sizes, int n_in,
                              void* d_out, int out_size, void* d_ws, size_t ws_size,
                              hipStream_t stream)
{
    const float* Q     = (const float*)d_in[0];
    const float* K     = (const float*)d_in[1];
    const float* V     = (const float*)d_in[2];
    const float* omega = (const float*)d_in[3];
    float* out = (float*)d_out;

    float* ws    = (float*)d_ws;
    float* Qp    = ws;                              // N*M
    float* A     = Qp    + (size_t)NTOT * MF;       // N*M
    float* KV    = A     + (size_t)NTOT * MF;       // B*M*DV
    float* Ksum  = KV    + (size_t)NB * MF * DVV;   // B*M
    float* rmaxA = Ksum  + (size_t)NB * MF;         // N
    float* smax  = rmaxA + NTOT;                    // B
    float* normv = smax  + NB;                      // N

    phi_kernel<false><<<NTOT / 64, 256, 0, stream>>>(K, omega, (const float*)nullptr, A, rmaxA);
    segmax_kernel<<<NB, 256, 0, stream>>>(rmaxA, smax);
    kv_kernel<<<dim3(2, 2, NB), 1024, 0, stream>>>(A, V, smax, KV, Ksum);
    phi_kernel<true ><<<NTOT / 64, 256, 0, stream>>>(Q, omega, Ksum, Qp, normv);
    out_kernel<<<dim3(2, 4, NB), 256, 0, stream>>>(Qp, KV, normv, out);
}

// Round 4
// 337.165 us; speedup vs baseline: 1.0895x; 1.0895x over previous
//
#include <hip/hip_runtime.h>
#include <math.h>

// Problem constants (fixed by the reference setup)
#define NTOT 32768
#define NB   64
#define NPB  512      // rows per segment
#define DQK  128
#define MF   256      // feature count m
#define DVV  256      // value dim

#define QK_SCALE   0.29730177875068026f   // 128^-0.25
#define INV_SQRT_M 0.0625f                // 1/sqrt(256)
#define EPS_PHI    1e-4f
#define EPS_NORM   1e-8f

static __device__ __forceinline__ float red_max32(float v) {
    v = fmaxf(v, __shfl_xor(v, 1, 64));
    v = fmaxf(v, __shfl_xor(v, 2, 64));
    v = fmaxf(v, __shfl_xor(v, 4, 64));
    v = fmaxf(v, __shfl_xor(v, 8, 64));
    v = fmaxf(v, __shfl_xor(v, 16, 64));
    return v;
}
static __device__ __forceinline__ float red_sum32(float v) {
    v += __shfl_xor(v, 1, 64);
    v += __shfl_xor(v, 2, 64);
    v += __shfl_xor(v, 4, 64);
    v += __shfl_xor(v, 8, 64);
    v += __shfl_xor(v, 16, 64);
    return v;
}

// ---------------------------------------------------------------------------
// Kernel 1: U = (X * d^-1/4) @ omega  [64 rows x all 256 cols per block]
// 256 threads: tx = tid&31, ty = tid>>5. 8x8 micro.
// B-frag columns split (tx*4, 128+tx*4) to avoid 8-way LDS conflicts.
//   IS_QUERY: out = Qp; aux = norm.   else: out = U - h; aux = rowmax(U)
// ---------------------------------------------------------------------------
template <bool IS_QUERY>
__global__ __launch_bounds__(256) void phi_kernel(
    const float* __restrict__ X, const float* __restrict__ omega,
    const float* __restrict__ Ksum,
    float* __restrict__ out, float* __restrict__ aux)
{
    __shared__ __align__(16) float xs[64][132];   // row-major
    __shared__ __align__(16) float oms[16][256];  // k-major omega chunk
    __shared__ float KsS[256];

    const int tid = threadIdx.x;
    const int tx  = tid & 31;
    const int ty  = tid >> 5;
    const int row0 = blockIdx.x * 64;

    if (IS_QUERY) KsS[tid] = Ksum[(row0 >> 9) * MF + tid];

    // ---- stage X tile (64x128), scaled, row-major ----
    {
        const float4* Xv = (const float4*)(X + (size_t)row0 * DQK);
        #pragma unroll
        for (int j = 0; j < 8; ++j) {
            int idx = tid + 256 * j;
            int r = idx >> 5, c4 = idx & 31;
            float4 v = Xv[idx];
            v.x *= QK_SCALE; v.y *= QK_SCALE; v.z *= QK_SCALE; v.w *= QK_SCALE;
            *(float4*)&xs[r][c4 * 4] = v;
        }
    }

    float acc[8][8] = {};
    float h[8] = {};

    const float4* Ov = (const float4*)omega;
    float4 oreg[4];
    #pragma unroll
    for (int j = 0; j < 4; ++j) oreg[j] = Ov[tid + 256 * j];

    for (int c = 0; c < 8; ++c) {
        __syncthreads();
        #pragma unroll
        for (int j = 0; j < 4; ++j) {
            int idx = tid + 256 * j;
            *(float4*)&oms[idx >> 6][(idx & 63) * 4] = oreg[j];
        }
        __syncthreads();
        if (c < 7) {
            #pragma unroll
            for (int j = 0; j < 4; ++j)
                oreg[j] = Ov[(c + 1) * 1024 + tid + 256 * j];
        }
        const int kc = c * 16;
        #pragma unroll
        for (int kq = 0; kq < 4; ++kq) {
            float4 a4[8];
            #pragma unroll
            for (int i = 0; i < 8; ++i)
                a4[i] = *(const float4*)&xs[ty * 8 + i][kc + kq * 4];
            #pragma unroll
            for (int t = 0; t < 4; ++t) {
                const int kk = kq * 4 + t;
                float4 b0 = *(const float4*)&oms[kk][tx * 4];
                float4 b1 = *(const float4*)&oms[kk][128 + tx * 4];
                float bv[8] = {b0.x, b0.y, b0.z, b0.w, b1.x, b1.y, b1.z, b1.w};
                #pragma unroll
                for (int i = 0; i < 8; ++i) {
                    const float av = ((const float*)&a4[i])[t];
                    h[i] = fmaf(av, av, h[i]);
                    #pragma unroll
                    for (int j = 0; j < 8; ++j)
                        acc[i][j] = fmaf(av, bv[j], acc[i][j]);
                }
            }
        }
    }

    // ---- epilogue (acc cols j<4 -> tx*4+j, j>=4 -> 128+tx*4+j-4) ----
    #pragma unroll
    for (int i = 0; i < 8; ++i) {
        const int grow = row0 + ty * 8 + i;
        float mx = acc[i][0];
        #pragma unroll
        for (int j = 1; j < 8; ++j) mx = fmaxf(mx, acc[i][j]);
        mx = red_max32(mx);
        const float hv = 0.5f * h[i];

        if (IS_QUERY) {
            const float hm = hv + mx;
            float q[8];
            #pragma unroll
            for (int j = 0; j < 8; ++j)
                q[j] = (__expf(acc[i][j] - hm) + EPS_PHI) * INV_SQRT_M;
            float4 o0 = {q[0], q[1], q[2], q[3]};
            float4 o1 = {q[4], q[5], q[6], q[7]};
            *(float4*)&out[(size_t)grow * MF + tx * 4]       = o0;
            *(float4*)&out[(size_t)grow * MF + 128 + tx * 4] = o1;
            float np = 0.f;
            #pragma unroll
            for (int j = 0; j < 4; ++j) np = fmaf(q[j], KsS[tx * 4 + j], np);
            #pragma unroll
            for (int j = 0; j < 4; ++j) np = fmaf(q[4 + j], KsS[128 + tx * 4 + j], np);
            np = red_sum32(np);
            if (tx == 0) aux[grow] = np;
        } else {
            float4 o0 = {acc[i][0] - hv, acc[i][1] - hv, acc[i][2] - hv, acc[i][3] - hv};
            float4 o1 = {acc[i][4] - hv, acc[i][5] - hv, acc[i][6] - hv, acc[i][7] - hv};
            *(float4*)&out[(size_t)grow * MF + tx * 4]       = o0;
            *(float4*)&out[(size_t)grow * MF + 128 + tx * 4] = o1;
            if (tx == 0) aux[grow] = mx;
        }
    }
}

// ---------------------------------------------------------------------------
// Kernel 2: segmax[b] = max over 512 rows of rmax
// ---------------------------------------------------------------------------
__global__ __launch_bounds__(256) void segmax_kernel(
    const float* __restrict__ rmax, float* __restrict__ segmax)
{
    const int b = blockIdx.x, tid = threadIdx.x;
    float v = fmaxf(rmax[b * NPB + tid], rmax[b * NPB + 256 + tid]);
    v = red_max32(v);
    v = fmaxf(v, __shfl_xor(v, 32, 64));
    __shared__ float red[4];
    if ((tid & 63) == 0) red[tid >> 6] = v;
    __syncthreads();
    if (tid == 0)
        segmax[b] = fmaxf(fmaxf(red[0], red[1]), fmaxf(red[2], red[3]));
}

// ---------------------------------------------------------------------------
// Kernel 3: KV[b] = Kp_b^T @ V_b, one 128x128 tile per 1024-thread block.
// Block-wide 4x4 micro-kernel: all 16 waves cooperate on ONE shared 64-row
// stage (Kps+Vs = 64 KB), looping all 8 n-chunks -> no cross-group combine,
// no atomics. Per-thread state (acc 16 + prefetch 16 + frags 8 ~ 55 VGPR)
// fits the 64-VGPR cap the compiler imposes on 1024-thread blocks (the
// (1024,*) 8x8-micro variants spilled acc to scratch: WRITE_SIZE 120MB).
// A-frag = 2-address broadcast; B-frag = two float2 at (lm4*2, 64+lm4*2),
// 2-way bank aliasing = free. vt==0 blocks also emit Ksum.
// ---------------------------------------------------------------------------
#define KVCH 64
__global__ __launch_bounds__(1024) void kv_kernel(
    const float* __restrict__ A, const float* __restrict__ V,
    const float* __restrict__ segmax,
    float* __restrict__ KV, float* __restrict__ Ksum)
{
    __shared__ __align__(16) float Kps[KVCH][128];   // 32 KB
    __shared__ __align__(16) float Vs [KVCH][128];   // 32 KB

    const int tid = threadIdx.x;
    const int ln  = tid >> 5;     // 0..31: stage row (+32j) / acc row-group
    const int lm4 = tid & 31;     // stage float4 col / acc col-group
    const int vt = blockIdx.x, mt = blockIdx.y, b = blockIdx.z;
    const int m0 = mt * 128, v0 = vt * 128;
    const size_t n0 = (size_t)b * NPB;
    const float smax = segmax[b];

    float acc[4][4] = {};
    float4 ks4 = {0.f, 0.f, 0.f, 0.f};

    float4 areg[2], vreg[2];
    #pragma unroll
    for (int j = 0; j < 2; ++j) {
        const size_t n = n0 + ln + 32 * j;
        areg[j] = *(const float4*)&A[n * MF + m0 + lm4 * 4];
        vreg[j] = *(const float4*)&V[n * DVV + v0 + lm4 * 4];
    }

    for (int c = 0; c < NPB / KVCH; ++c) {
        __syncthreads();
        #pragma unroll
        for (int j = 0; j < 2; ++j) {
            float4 e;
            e.x = (__expf(areg[j].x - smax) + EPS_PHI) * INV_SQRT_M;
            e.y = (__expf(areg[j].y - smax) + EPS_PHI) * INV_SQRT_M;
            e.z = (__expf(areg[j].z - smax) + EPS_PHI) * INV_SQRT_M;
            e.w = (__expf(areg[j].w - smax) + EPS_PHI) * INV_SQRT_M;
            ks4.x += e.x; ks4.y += e.y; ks4.z += e.z; ks4.w += e.w;
            *(float4*)&Kps[ln + 32 * j][lm4 * 4] = e;
            *(float4*)&Vs [ln + 32 * j][lm4 * 4] = vreg[j];
        }
        __syncthreads();
        if (c < NPB / KVCH - 1) {
            #pragma unroll
            for (int j = 0; j < 2; ++j) {
                const size_t n = n0 + (c + 1) * KVCH + ln + 32 * j;
                areg[j] = *(const float4*)&A[n * MF + m0 + lm4 * 4];
                vreg[j] = *(const float4*)&V[n * DVV + v0 + lm4 * 4];
            }
        }
        #pragma unroll 8
        for (int kk = 0; kk < KVCH; ++kk) {
            float4 a4 = *(const float4*)&Kps[kk][ln * 4];
            float2 bl = *(const float2*)&Vs[kk][lm4 * 2];
            float2 bh = *(const float2*)&Vs[kk][64 + lm4 * 2];
            float av[4] = {a4.x, a4.y, a4.z, a4.w};
            #pragma unroll
            for (int i = 0; i < 4; ++i) {
                acc[i][0] = fmaf(av[i], bl.x, acc[i][0]);
                acc[i][1] = fmaf(av[i], bl.y, acc[i][1]);
                acc[i][2] = fmaf(av[i], bh.x, acc[i][2]);
                acc[i][3] = fmaf(av[i], bh.y, acc[i][3]);
            }
        }
    }

    // ---- store: thread (ln,lm4) owns rows m0+ln*4..+3, cols {lm4*2,+1, 64+lm4*2,+1}
    #pragma unroll
    for (int i = 0; i < 4; ++i) {
        const size_t base = ((size_t)b * MF + m0 + ln * 4 + i) * DVV + v0;
        float2 o0 = {acc[i][0], acc[i][1]};
        float2 o1 = {acc[i][2], acc[i][3]};
        *(float2*)&KV[base + lm4 * 2]      = o0;
        *(float2*)&KV[base + 64 + lm4 * 2] = o1;
    }

    // ---- Ksum: per-thread column partials -> LDS [32][128] -> 128-thread sum
    if (vt == 0) {
        __syncthreads();                       // all compute reads of Kps done
        *(float4*)&Kps[ln][lm4 * 4] = ks4;     // scratch [32][128]
        __syncthreads();
        if (tid < 128) {
            float s = 0.f;
            #pragma unroll
            for (int r = 0; r < 32; ++r) s += Kps[r][tid];
            Ksum[b * MF + m0 + tid] = s;
        }
    }
}

// ---------------------------------------------------------------------------
// Kernel 4: out = (Qp @ KV[b]) / (norm + eps). 128 rows x 128 v per block,
// 8x8 micro, m-chunk 32, register-prefetch pipeline.
// A-frag rows split (ty*4, 64+ty*4); B-frag cols split (tx*4, 64+tx*4).
// ---------------------------------------------------------------------------
__global__ __launch_bounds__(256) void out_kernel(
    const float* __restrict__ Qp, const float* __restrict__ KVm,
    const float* __restrict__ normv, float* __restrict__ out)
{
    __shared__ __align__(16) float Qs[128][36];   // row-major
    __shared__ __align__(16) float KVs[32][128];  // k-major
    __shared__ float nrmS[128];

    const int tid = threadIdx.x;
    const int tx = tid & 15, ty = tid >> 4;
    const int vt = blockIdx.x, rt = blockIdx.y, b = blockIdx.z;
    const int v0 = vt * 128;
    const int r0 = b * NPB + rt * 128;

    if (tid < 128) nrmS[tid] = normv[r0 + tid];

    const int qr  = tid >> 3;     // 0..31 (+32j)
    const int qm4 = tid & 7;
    const int km  = tid >> 5;     // 0..7  (+8j)
    const int kv4 = tid & 31;

    float acc[8][8] = {};

    float4 qreg[4], kreg[4];
    #pragma unroll
    for (int j = 0; j < 4; ++j) {
        qreg[j] = *(const float4*)&Qp[(size_t)(r0 + qr + 32 * j) * MF + qm4 * 4];
        kreg[j] = *(const float4*)&KVm[((size_t)b * MF + km + 8 * j) * DVV + v0 + kv4 * 4];
    }

    for (int c = 0; c < 8; ++c) {
        __syncthreads();
        #pragma unroll
        for (int j = 0; j < 4; ++j) {
            *(float4*)&Qs[qr + 32 * j][qm4 * 4]  = qreg[j];
            *(float4*)&KVs[km + 8 * j][kv4 * 4] = kreg[j];
        }
        __syncthreads();
        if (c < 7) {
            const int mc = (c + 1) * 32;
            #pragma unroll
            for (int j = 0; j < 4; ++j) {
                qreg[j] = *(const float4*)&Qp[(size_t)(r0 + qr + 32 * j) * MF + mc + qm4 * 4];
                kreg[j] = *(const float4*)&KVm[((size_t)b * MF + mc + km + 8 * j) * DVV + v0 + kv4 * 4];
            }
        }
        #pragma unroll 2
        for (int kq = 0; kq < 8; ++kq) {
            float4 a4[8];
            #pragma unroll
            for (int i = 0; i < 4; ++i)
                a4[i] = *(const float4*)&Qs[ty * 4 + i][kq * 4];
            #pragma unroll
            for (int i = 0; i < 4; ++i)
                a4[4 + i] = *(const float4*)&Qs[64 + ty * 4 + i][kq * 4];
            #pragma unroll
            for (int t = 0; t < 4; ++t) {
                const int kk = kq * 4 + t;
                float4 b0 = *(const float4*)&KVs[kk][tx * 4];
                float4 b1 = *(const float4*)&KVs[kk][64 + tx * 4];
                float bv[8] = {b0.x, b0.y, b0.z, b0.w, b1.x, b1.y, b1.z, b1.w};
                #pragma unroll
                for (int i = 0; i < 8; ++i) {
                    const float av = ((const float*)&a4[i])[t];
                    #pragma unroll
                    for (int j = 0; j < 8; ++j)
                        acc[i][j] = fmaf(av, bv[j], acc[i][j]);
                }
            }
        }
    }

    #pragma unroll
    for (int i = 0; i < 8; ++i) {
        const int row = (i < 4) ? (ty * 4 + i) : (64 + ty * 4 + i - 4);
        const float inv = 1.0f / (nrmS[row] + EPS_NORM);
        float4 o0 = {acc[i][0] * inv, acc[i][1] * inv, acc[i][2] * inv, acc[i][3] * inv};
        float4 o1 = {acc[i][4] * inv, acc[i][5] * inv, acc[i][6] * inv, acc[i][7] * inv};
        const size_t base = (size_t)(r0 + row) * DVV + v0;
        *(float4*)&out[base + tx * 4]      = o0;
        *(float4*)&out[base + 64 + tx * 4] = o1;
    }
}

// ---------------------------------------------------------------------------
extern "C" void kernel_launch(void* const* d_in, const int* in_sizes, int n_in,
                              void* d_out, int out_size, void* d_ws, size_t ws_size,
                              hipStream_t stream)
{
    const float* Q     = (const float*)d_in[0];
    const float* K     = (const float*)d_in[1];
    const float* V     = (const float*)d_in[2];
    const float* omega = (const float*)d_in[3];
    float* out = (float*)d_out;

    float* ws    = (float*)d_ws;
    float* Qp    = ws;                              // N*M
    float* A     = Qp    + (size_t)NTOT * MF;       // N*M
    float* KV    = A     + (size_t)NTOT * MF;       // B*M*DV
    float* Ksum  = KV    + (size_t)NB * MF * DVV;   // B*M
    float* rmaxA = Ksum  + (size_t)NB * MF;         // N
    float* smax  = rmaxA + NTOT;                    // B
    float* normv = smax  + NB;                      // N

    phi_kernel<false><<<NTOT / 64, 256, 0, stream>>>(K, omega, (const float*)nullptr, A, rmaxA);
    segmax_kernel<<<NB, 256, 0, stream>>>(rmaxA, smax);
    kv_kernel<<<dim3(2, 2, NB), 1024, 0, stream>>>(A, V, smax, KV, Ksum);
    phi_kernel<true ><<<NTOT / 64, 256, 0, stream>>>(Q, omega, Ksum, Qp, normv);
    out_kernel<<<dim3(2, 4, NB), 256, 0, stream>>>(Qp, KV, normv, out);
}

// Round 5
// 323.629 us; speedup vs baseline: 1.1351x; 1.0418x over previous
//
#include <hip/hip_runtime.h>
#include <math.h>

// Problem constants (fixed by the reference setup)
#define NTOT 32768
#define NB   64
#define NPB  512      // rows per segment
#define DQK  128
#define MF   256      // feature count m
#define DVV  256      // value dim

#define QK_SCALE   0.29730177875068026f   // 128^-0.25
#define INV_SQRT_M 0.0625f                // 1/sqrt(256)
#define EPS_PHI    1e-4f
#define EPS_NORM   1e-8f
#define EPS_ISM    (EPS_PHI * INV_SQRT_M)

static __device__ __forceinline__ float red_max32(float v) {
    v = fmaxf(v, __shfl_xor(v, 1, 64));
    v = fmaxf(v, __shfl_xor(v, 2, 64));
    v = fmaxf(v, __shfl_xor(v, 4, 64));
    v = fmaxf(v, __shfl_xor(v, 8, 64));
    v = fmaxf(v, __shfl_xor(v, 16, 64));
    return v;
}
static __device__ __forceinline__ float red_sum32(float v) {
    v += __shfl_xor(v, 1, 64);
    v += __shfl_xor(v, 2, 64);
    v += __shfl_xor(v, 4, 64);
    v += __shfl_xor(v, 8, 64);
    v += __shfl_xor(v, 16, 64);
    return v;
}

// ---------------------------------------------------------------------------
// Kernel 1: U = (X * d^-1/4) @ omega  [64 rows x all 256 cols per block]
// 256 threads, 8x8 micro. NO register prefetch (global->LDS between barriers;
// 2 blocks/CU TLP hides staging latency) and NO a4-hold: A-frag is a
// 32-lane-broadcast scalar LDS read (bank-free), so per-thread live set is
// ~100 VGPR -> spill-free under the __launch_bounds__(256,4) 128-VGPR cap.
//   IS_QUERY: out = Qp = (exp(U-h-rowmax)+eps)/sqrt(m); aux = norm
//   else:     out = exp(U - h - rowmax)  (exp moved here from kv); aux = rowmax
// ---------------------------------------------------------------------------
template <bool IS_QUERY>
__global__ __launch_bounds__(256, 4) void phi_kernel(
    const float* __restrict__ X, const float* __restrict__ omega,
    const float* __restrict__ Ksum,
    float* __restrict__ out, float* __restrict__ aux)
{
    __shared__ __align__(16) float xs[64][132];   // row-major (+4 pad: banks shift by 4/row)
    __shared__ __align__(16) float oms[16][256];  // k-major omega chunk
    __shared__ float KsS[256];

    const int tid = threadIdx.x;
    const int tx  = tid & 31;
    const int ty  = tid >> 5;
    const int row0 = blockIdx.x * 64;

    if (IS_QUERY) KsS[tid] = Ksum[(row0 >> 9) * MF + tid];

    // ---- stage X tile (64x128), scaled, row-major ----
    {
        const float4* Xv = (const float4*)(X + (size_t)row0 * DQK);
        #pragma unroll
        for (int j = 0; j < 8; ++j) {
            int idx = tid + 256 * j;
            int r = idx >> 5, c4 = idx & 31;
            float4 v = Xv[idx];
            v.x *= QK_SCALE; v.y *= QK_SCALE; v.z *= QK_SCALE; v.w *= QK_SCALE;
            *(float4*)&xs[r][c4 * 4] = v;
        }
    }

    float acc[8][8] = {};
    float h[8] = {};

    const float4* Ov = (const float4*)omega;

    for (int c = 0; c < 8; ++c) {
        __syncthreads();
        #pragma unroll
        for (int j = 0; j < 4; ++j) {
            int idx = tid + 256 * j;
            *(float4*)&oms[idx >> 6][(idx & 63) * 4] = Ov[c * 1024 + idx];
        }
        __syncthreads();
        const int kc = c * 16;
        #pragma unroll 4
        for (int kk = 0; kk < 16; ++kk) {
            float4 b0 = *(const float4*)&oms[kk][tx * 4];
            float4 b1 = *(const float4*)&oms[kk][128 + tx * 4];
            float bv[8] = {b0.x, b0.y, b0.z, b0.w, b1.x, b1.y, b1.z, b1.w};
            #pragma unroll
            for (int i = 0; i < 8; ++i) {
                const float av = xs[ty * 8 + i][kc + kk];   // broadcast read
                h[i] = fmaf(av, av, h[i]);
                #pragma unroll
                for (int j = 0; j < 8; ++j)
                    acc[i][j] = fmaf(av, bv[j], acc[i][j]);
            }
        }
    }

    // ---- epilogue (acc cols j<4 -> tx*4+j, j>=4 -> 128+tx*4+j-4) ----
    #pragma unroll
    for (int i = 0; i < 8; ++i) {
        const int grow = row0 + ty * 8 + i;
        float mx = acc[i][0];
        #pragma unroll
        for (int j = 1; j < 8; ++j) mx = fmaxf(mx, acc[i][j]);
        mx = red_max32(mx);
        const float hv = 0.5f * h[i];
        const float hm = hv + mx;

        if (IS_QUERY) {
            float q[8];
            #pragma unroll
            for (int j = 0; j < 8; ++j)
                q[j] = (__expf(acc[i][j] - hm) + EPS_PHI) * INV_SQRT_M;
            float4 o0 = {q[0], q[1], q[2], q[3]};
            float4 o1 = {q[4], q[5], q[6], q[7]};
            *(float4*)&out[(size_t)grow * MF + tx * 4]       = o0;
            *(float4*)&out[(size_t)grow * MF + 128 + tx * 4] = o1;
            float np = 0.f;
            #pragma unroll
            for (int j = 0; j < 4; ++j) np = fmaf(q[j], KsS[tx * 4 + j], np);
            #pragma unroll
            for (int j = 0; j < 4; ++j) np = fmaf(q[4 + j], KsS[128 + tx * 4 + j], np);
            np = red_sum32(np);
            if (tx == 0) aux[grow] = np;
        } else {
            float4 o0 = {__expf(acc[i][0] - hm), __expf(acc[i][1] - hm),
                         __expf(acc[i][2] - hm), __expf(acc[i][3] - hm)};
            float4 o1 = {__expf(acc[i][4] - hm), __expf(acc[i][5] - hm),
                         __expf(acc[i][6] - hm), __expf(acc[i][7] - hm)};
            *(float4*)&out[(size_t)grow * MF + tx * 4]       = o0;
            *(float4*)&out[(size_t)grow * MF + 128 + tx * 4] = o1;
            if (tx == 0) aux[grow] = mx;
        }
    }
}

// ---------------------------------------------------------------------------
// Kernel 2: sexp[n] = exp(rmax[n] - max_{segment} rmax)  (segmax broadcast +
// per-row scale, so kv needs only one fmaf per staged element, no exp).
// ---------------------------------------------------------------------------
__global__ __launch_bounds__(256) void segsexp_kernel(
    const float* __restrict__ rmax, float* __restrict__ sexp)
{
    const int b = blockIdx.x, tid = threadIdx.x;
    const float r0 = rmax[b * NPB + tid];
    const float r1 = rmax[b * NPB + 256 + tid];
    float v = fmaxf(r0, r1);
    v = red_max32(v);
    v = fmaxf(v, __shfl_xor(v, 32, 64));
    __shared__ float red[4];
    if ((tid & 63) == 0) red[tid >> 6] = v;
    __syncthreads();
    const float smax = fmaxf(fmaxf(red[0], red[1]), fmaxf(red[2], red[3]));
    sexp[b * NPB + tid]       = __expf(r0 - smax);
    sexp[b * NPB + 256 + tid] = __expf(r1 - smax);
}

// ---------------------------------------------------------------------------
// Kernel 3: KV partial = Kp_chunk^T @ V_chunk over 256 rows (2-way n-split ->
// 512 blocks = 2 blocks/CU). 256 threads, 8x8 micro, NO prefetch regs, NO
// a4-hold (A-frag = 16-lane-broadcast scalar reads over 4 distinct banks).
// Kp = (A' * sexp[n] + eps)/sqrt(m) folded to one fmaf (A' = exp(U-h-rmax)
// from phi_K). ch==0 writes KV + Ksum; ch==1 writes partials (KVp = the idle
// Qp buffer, zero extra workspace) combined by kvreduce_kernel. No atomics.
// ---------------------------------------------------------------------------
__global__ __launch_bounds__(256, 4) void kv_kernel(
    const float* __restrict__ A, const float* __restrict__ V,
    const float* __restrict__ sexp,
    float* __restrict__ KV, float* __restrict__ KVp,
    float* __restrict__ Ksum, float* __restrict__ KsumP)
{
    __shared__ __align__(16) float Kps[32][128];
    __shared__ __align__(16) float Vs[32][128];

    const int tid = threadIdx.x;
    const int tx = tid & 15, ty = tid >> 4;
    const int vt = blockIdx.x, mt = blockIdx.y;
    const int b  = blockIdx.z >> 1, ch = blockIdx.z & 1;
    const int m0 = mt * 128, v0 = vt * 128;
    const size_t n0 = (size_t)b * NPB + ch * 256;

    const int ln  = tid >> 5;     // 0..7  (n within chunk, +8j)
    const int lm4 = tid & 31;     // float4 column

    float acc[8][8] = {};
    float4 ks4 = {0.f, 0.f, 0.f, 0.f};

    for (int c = 0; c < 8; ++c) {
        __syncthreads();
        #pragma unroll
        for (int j = 0; j < 4; ++j) {
            const size_t n = n0 + c * 32 + ln + 8 * j;
            float4 a  = *(const float4*)&A[n * MF + m0 + lm4 * 4];
            float4 vv = *(const float4*)&V[n * DVV + v0 + lm4 * 4];
            const float s2 = sexp[n] * INV_SQRT_M;
            float4 e;
            e.x = fmaf(a.x, s2, EPS_ISM);
            e.y = fmaf(a.y, s2, EPS_ISM);
            e.z = fmaf(a.z, s2, EPS_ISM);
            e.w = fmaf(a.w, s2, EPS_ISM);
            ks4.x += e.x; ks4.y += e.y; ks4.z += e.z; ks4.w += e.w;
            *(float4*)&Kps[ln + 8 * j][lm4 * 4] = e;
            *(float4*)&Vs [ln + 8 * j][lm4 * 4] = vv;
        }
        __syncthreads();
        #pragma unroll 8
        for (int kk = 0; kk < 32; ++kk) {
            float4 b0 = *(const float4*)&Vs[kk][tx * 4];
            float4 b1 = *(const float4*)&Vs[kk][64 + tx * 4];
            float bv[8] = {b0.x, b0.y, b0.z, b0.w, b1.x, b1.y, b1.z, b1.w};
            #pragma unroll
            for (int i = 0; i < 8; ++i) {
                const float av = Kps[kk][ty * 8 + i];   // broadcast read
                #pragma unroll
                for (int j = 0; j < 8; ++j)
                    acc[i][j] = fmaf(av, bv[j], acc[i][j]);
            }
        }
    }

    float* __restrict__ dKV = ch ? KVp : KV;
    #pragma unroll
    for (int i = 0; i < 8; ++i) {
        const size_t base = ((size_t)b * MF + m0 + ty * 8 + i) * DVV + v0;
        float4 o0 = {acc[i][0], acc[i][1], acc[i][2], acc[i][3]};
        float4 o1 = {acc[i][4], acc[i][5], acc[i][6], acc[i][7]};
        *(float4*)&dKV[base + tx * 4]      = o0;
        *(float4*)&dKV[base + 64 + tx * 4] = o1;
    }

    if (vt == 0) {
        __syncthreads();                       // compute reads of Kps done
        *(float4*)&Kps[ln][lm4 * 4] = ks4;     // scratch [8][128]
        __syncthreads();
        if (tid < 128) {
            float s = 0.f;
            #pragma unroll
            for (int g = 0; g < 8; ++g) s += Kps[g][tid];
            (ch ? KsumP : Ksum)[b * MF + m0 + tid] = s;
        }
    }
}

// ---------------------------------------------------------------------------
// Kernel 3b: fold the ch==1 partials into KV / Ksum.
// ---------------------------------------------------------------------------
__global__ __launch_bounds__(256) void kvreduce_kernel(
    float* __restrict__ KV, const float* __restrict__ KVp,
    float* __restrict__ Ksum, const float* __restrict__ KsumP)
{
    const int idx = blockIdx.x * 256 + threadIdx.x;
    const int stride = gridDim.x * 256;
    const int TOT4 = NB * MF * DVV / 4;
    for (int i = idx; i < TOT4; i += stride) {
        float4 a = ((const float4*)KV)[i];
        float4 p = ((const float4*)KVp)[i];
        a.x += p.x; a.y += p.y; a.z += p.z; a.w += p.w;
        ((float4*)KV)[i] = a;
    }
    const int KS4 = NB * MF / 4;
    for (int i = idx; i < KS4; i += stride) {
        float4 a = ((const float4*)Ksum)[i];
        float4 p = ((const float4*)KsumP)[i];
        a.x += p.x; a.y += p.y; a.z += p.z; a.w += p.w;
        ((float4*)Ksum)[i] = a;
    }
}

// ---------------------------------------------------------------------------
// Kernel 4: out = (Qp @ KV[b]) / (norm + eps). 128 rows x 128 v per block,
// 8x8 micro. NO prefetch regs, NO a4-hold (A-frag scalar broadcast reads).
// A-frag rows split (ty*4, 64+ty*4); B-frag cols split (tx*4, 64+tx*4).
// ---------------------------------------------------------------------------
__global__ __launch_bounds__(256, 4) void out_kernel(
    const float* __restrict__ Qp, const float* __restrict__ KVm,
    const float* __restrict__ normv, float* __restrict__ out)
{
    __shared__ __align__(16) float Qs[128][36];   // row-major (36: float4-aligned pad)
    __shared__ __align__(16) float KVs[32][128];  // k-major
    __shared__ float nrmS[128];

    const int tid = threadIdx.x;
    const int tx = tid & 15, ty = tid >> 4;
    const int vt = blockIdx.x, rt = blockIdx.y, b = blockIdx.z;
    const int v0 = vt * 128;
    const int r0 = b * NPB + rt * 128;

    if (tid < 128) nrmS[tid] = normv[r0 + tid];

    const int qr  = tid >> 3;     // 0..31 (+32j)
    const int qm4 = tid & 7;
    const int km  = tid >> 5;     // 0..7  (+8j)
    const int kv4 = tid & 31;

    float acc[8][8] = {};

    for (int c = 0; c < 8; ++c) {
        __syncthreads();
        const int mc = c * 32;
        #pragma unroll
        for (int j = 0; j < 4; ++j) {
            *(float4*)&Qs[qr + 32 * j][qm4 * 4] =
                *(const float4*)&Qp[(size_t)(r0 + qr + 32 * j) * MF + mc + qm4 * 4];
            *(float4*)&KVs[km + 8 * j][kv4 * 4] =
                *(const float4*)&KVm[((size_t)b * MF + mc + km + 8 * j) * DVV + v0 + kv4 * 4];
        }
        __syncthreads();
        #pragma unroll 4
        for (int kk = 0; kk < 32; ++kk) {
            float4 b0 = *(const float4*)&KVs[kk][tx * 4];
            float4 b1 = *(const float4*)&KVs[kk][64 + tx * 4];
            float bv[8] = {b0.x, b0.y, b0.z, b0.w, b1.x, b1.y, b1.z, b1.w};
            #pragma unroll
            for (int i = 0; i < 8; ++i) {
                const int row = (i < 4) ? (ty * 4 + i) : (64 + ty * 4 + i - 4);
                const float av = Qs[row][kk];           // broadcast read
                #pragma unroll
                for (int j = 0; j < 8; ++j)
                    acc[i][j] = fmaf(av, bv[j], acc[i][j]);
            }
        }
    }

    #pragma unroll
    for (int i = 0; i < 8; ++i) {
        const int row = (i < 4) ? (ty * 4 + i) : (64 + ty * 4 + i - 4);
        const float inv = 1.0f / (nrmS[row] + EPS_NORM);
        float4 o0 = {acc[i][0] * inv, acc[i][1] * inv, acc[i][2] * inv, acc[i][3] * inv};
        float4 o1 = {acc[i][4] * inv, acc[i][5] * inv, acc[i][6] * inv, acc[i][7] * inv};
        const size_t base = (size_t)(r0 + row) * DVV + v0;
        *(float4*)&out[base + tx * 4]      = o0;
        *(float4*)&out[base + 64 + tx * 4] = o1;
    }
}

// ---------------------------------------------------------------------------
extern "C" void kernel_launch(void* const* d_in, const int* in_sizes, int n_in,
                              void* d_out, int out_size, void* d_ws, size_t ws_size,
                              hipStream_t stream)
{
    const float* Q     = (const float*)d_in[0];
    const float* K     = (const float*)d_in[1];
    const float* V     = (const float*)d_in[2];
    const float* omega = (const float*)d_in[3];
    float* out = (float*)d_out;

    float* ws    = (float*)d_ws;
    float* Qp    = ws;                              // N*M  (doubles as KVp scratch during kv)
    float* A     = Qp    + (size_t)NTOT * MF;       // N*M   A' = exp(U-h-rmax)
    float* KV    = A     + (size_t)NTOT * MF;       // B*M*DV
    float* Ksum  = KV    + (size_t)NB * MF * DVV;   // B*M
    float* KsumP = Ksum  + (size_t)NB * MF;         // B*M
    float* rmaxA = KsumP + (size_t)NB * MF;         // N
    float* sexp  = rmaxA + NTOT;                    // N
    float* normv = sexp  + NTOT;                    // N

    phi_kernel<false><<<NTOT / 64, 256, 0, stream>>>(K, omega, (const float*)nullptr, A, rmaxA);
    segsexp_kernel<<<NB, 256, 0, stream>>>(rmaxA, sexp);
    kv_kernel<<<dim3(2, 2, NB * 2), 256, 0, stream>>>(A, V, sexp, KV, Qp, Ksum, KsumP);
    kvreduce_kernel<<<2048, 256, 0, stream>>>(KV, Qp, Ksum, KsumP);
    phi_kernel<true ><<<NTOT / 64, 256, 0, stream>>>(Q, omega, Ksum, Qp, normv);
    out_kernel<<<dim3(2, 4, NB), 256, 0, stream>>>(Qp, KV, normv, out);
}